// Round 10
// baseline (348.184 us; speedup 1.0000x reference)
//
#include <hip/hip_runtime.h>
#include <hip/hip_bf16.h>

typedef short s8v  __attribute__((ext_vector_type(8)));
typedef float f16v __attribute__((ext_vector_type(16)));

__device__ __forceinline__ unsigned short f2bf(float x) {   // RTN-even
    unsigned u = __float_as_uint(x);
    unsigned r = ((u >> 16) & 1u) + 0x7FFFu;
    return (unsigned short)((u + r) >> 16);
}
__device__ __forceinline__ float bf2f(unsigned short h) {
    return __uint_as_float(((unsigned)h) << 16);
}

// ---------------- X0 = ent_tab[entity] ----------------
__global__ __launch_bounds__(256) void x0_kernel(
    const float* __restrict__ tab, const int* __restrict__ entity,
    float* __restrict__ X0, int N)
{
    int idx = blockIdx.x * 256 + threadIdx.x;
    int n = idx >> 5, l = idx & 31;
    if (n < N) {
        int src = entity[n];
        *(float4*)&X0[(size_t)n * 128 + l * 4] =
            *(const float4*)&tab[(size_t)src * 128 + l * 4];
    }
}

// ---------------- B prep: fragment-packed Bp[k>>3][col][8] hi/lo ----------------
// k<512: basis[k&3][k>>2][n]; k>=512: root[k-512][n]
__global__ __launch_bounds__(256) void bprep_kernel(
    const float* __restrict__ basis1, const float* __restrict__ root1,
    const float* __restrict__ basis2, const float* __restrict__ root2,
    unsigned short* __restrict__ Bp1h, unsigned short* __restrict__ Bp1l,
    unsigned short* __restrict__ Bp2h, unsigned short* __restrict__ Bp2l)
{
    int idx = blockIdx.x * 256 + threadIdx.x;    // 0..81919
    int layer = blockIdx.y;
    int n = idx & 127, k = idx >> 7;             // k 0..639
    const float* basis = layer ? basis2 : basis1;
    const float* root  = layer ? root2  : root1;
    float v = (k < 512) ? basis[((k & 3) << 14) + ((k >> 2) << 7) + n]
                        : root[((k - 512) << 7) + n];
    unsigned short h = f2bf(v);
    unsigned short l = f2bf(v - bf2f(h));
    size_t pos = (((size_t)(k >> 3) * 128) + n) * 8 + (k & 7);
    unsigned short* Bh = layer ? Bp2h : Bp1h;
    unsigned short* Bl = layer ? Bp2l : Bp1l;
    Bh[pos] = h;
    Bl[pos] = l;
}

// ---------------- CSR build ----------------
__global__ __launch_bounds__(256) void hist_kernel(
    const int* __restrict__ edge_index, int* __restrict__ deg, int E)
{
    int e = blockIdx.x * 256 + threadIdx.x;
    if (e < E) atomicAdd(&deg[edge_index[E + e]], 1);
}

__global__ __launch_bounds__(1024) void scanA_kernel(
    const int* __restrict__ deg, int* __restrict__ row_start,
    int* __restrict__ btot, int N)
{
    __shared__ int wtot[16];
    __shared__ int woff[16];
    const int tid = threadIdx.x, lane = tid & 63, wid = tid >> 6;
    int i = blockIdx.x * 1024 + tid;
    int v = (i < N) ? deg[i] : 0;
    int x = v;
    #pragma unroll
    for (int d = 1; d < 64; d <<= 1) {
        int t = __shfl_up(x, d, 64);
        if (lane >= d) x += t;
    }
    if (lane == 63) wtot[wid] = x;
    __syncthreads();
    if (wid == 0 && lane < 16) {
        int s = wtot[lane];
        int y = s;
        #pragma unroll
        for (int d = 1; d < 16; d <<= 1) {
            int t = __shfl_up(y, d, 16);
            if (lane >= d) y += t;
        }
        woff[lane] = y - s;
        if (lane == 15) btot[blockIdx.x] = y;
    }
    __syncthreads();
    if (i < N) row_start[i] = woff[wid] + (x - v);
}

__global__ __launch_bounds__(64) void scanB_kernel(
    const int* __restrict__ btot, int* __restrict__ boff,
    int* __restrict__ row_start, int nB, int N)
{
    int t = threadIdx.x;
    int v = (t < nB) ? btot[t] : 0;
    int x = v;
    #pragma unroll
    for (int d = 1; d < 64; d <<= 1) {
        int u = __shfl_up(x, d, 64);
        if (t >= d) x += u;
    }
    if (t < nB) boff[t] = x - v;
    if (t == nB - 1) row_start[N] = x;
}

__global__ __launch_bounds__(1024) void scanC_kernel(
    int* __restrict__ row_start, int* __restrict__ cursor,
    const int* __restrict__ boff, int N)
{
    int i = blockIdx.x * 1024 + threadIdx.x;
    if (i < N) {
        int r = row_start[i] + boff[blockIdx.x];
        row_start[i] = r;
        cursor[i]    = r;
    }
}

// fill: reorder by destination; precompute norm*att for BOTH layers (kills et-indirection)
__global__ __launch_bounds__(256) void fill_kernel(
    const int* __restrict__ edge_index, const int* __restrict__ edge_type,
    const float* __restrict__ edge_norm, int* __restrict__ cursor,
    const float* __restrict__ att1, const float* __restrict__ att2,
    int* __restrict__ src_s, float4* __restrict__ an1, float4* __restrict__ an2, int E)
{
    int e = blockIdx.x * 256 + threadIdx.x;
    if (e >= E) return;
    int dst = edge_index[E + e];
    int et  = edge_type[e];
    float n = edge_norm[e];
    int pos = atomicAdd(&cursor[dst], 1);
    src_s[pos] = edge_index[e];
    float4 a1 = *(const float4*)&att1[(size_t)et * 4];
    float4 a2 = *(const float4*)&att2[(size_t)et * 4];
    an1[pos] = make_float4(n * a1.x, n * a1.y, n * a1.z, n * a1.w);
    an2[pos] = make_float4(n * a2.x, n * a2.y, n * a2.z, n * a2.w);
}

// ---------------- edge agg: 4 edges in flight per iteration ----------------
// w[n, 16l + 4d + b] = (sum_e an[b] * x[src, 4l+d]) / cnt  -> bf16
__global__ __launch_bounds__(256) void edge_agg_kernel(
    const float* __restrict__ X,
    const int* __restrict__ row_start,
    const int* __restrict__ src_s,
    const float4* __restrict__ an,
    unsigned short* __restrict__ w, int N)
{
    int n = blockIdx.x * 8 + (threadIdx.x >> 5);
    if (n >= N) return;
    int l = threadIdx.x & 31;           // dims 4l..4l+3
    int s0 = row_start[n], s1 = row_start[n + 1];
    float acc[4][4];
    #pragma unroll
    for (int d = 0; d < 4; ++d)
        #pragma unroll
        for (int b = 0; b < 4; ++b) acc[d][b] = 0.f;

    for (int p = s0; p < s1; p += 4) {
        int i1 = min(p + 1, s1 - 1);
        int i2 = min(p + 2, s1 - 1);
        int i3 = min(p + 3, s1 - 1);
        int sA = src_s[p],  sB = src_s[i1];
        int sC = src_s[i2], sD = src_s[i3];
        float4 aA = an[p],  aB = an[i1];
        float4 aC = an[i2], aD = an[i3];
        if (p + 1 >= s1) aB = make_float4(0.f, 0.f, 0.f, 0.f);
        if (p + 2 >= s1) aC = make_float4(0.f, 0.f, 0.f, 0.f);
        if (p + 3 >= s1) aD = make_float4(0.f, 0.f, 0.f, 0.f);
        float4 xA = *(const float4*)&X[(size_t)sA * 128 + (l << 2)];
        float4 xB = *(const float4*)&X[(size_t)sB * 128 + (l << 2)];
        float4 xC = *(const float4*)&X[(size_t)sC * 128 + (l << 2)];
        float4 xD = *(const float4*)&X[(size_t)sD * 128 + (l << 2)];
        float xsA[4] = {xA.x, xA.y, xA.z, xA.w};
        float xsB[4] = {xB.x, xB.y, xB.z, xB.w};
        float xsC[4] = {xC.x, xC.y, xC.z, xC.w};
        float xsD[4] = {xD.x, xD.y, xD.z, xD.w};
        #pragma unroll
        for (int d = 0; d < 4; ++d) {
            acc[d][0] = fmaf(aA.x, xsA[d], fmaf(aB.x, xsB[d], fmaf(aC.x, xsC[d], fmaf(aD.x, xsD[d], acc[d][0]))));
            acc[d][1] = fmaf(aA.y, xsA[d], fmaf(aB.y, xsB[d], fmaf(aC.y, xsC[d], fmaf(aD.y, xsD[d], acc[d][1]))));
            acc[d][2] = fmaf(aA.z, xsA[d], fmaf(aB.z, xsB[d], fmaf(aC.z, xsC[d], fmaf(aD.z, xsD[d], acc[d][2]))));
            acc[d][3] = fmaf(aA.w, xsA[d], fmaf(aB.w, xsB[d], fmaf(aC.w, xsC[d], fmaf(aD.w, xsD[d], acc[d][3]))));
        }
    }
    float inv = 1.0f / fmaxf((float)(s1 - s0), 1.0f);
    #pragma unroll
    for (int d = 0; d < 4; ++d) {
        ushort4 h;
        h.x = f2bf(acc[d][0] * inv);
        h.y = f2bf(acc[d][1] * inv);
        h.z = f2bf(acc[d][2] * inv);
        h.w = f2bf(acc[d][3] * inv);
        *(ushort4*)&w[(size_t)n * 512 + (l << 4) + (d << 2)] = h;
    }
}

// ---------------- GEMM K=640, 32x32x16 MFMA, B direct global->reg ----------------
// 64 rows x 128 cols per block; wave = (row-half 32, col-half 64 = 2 tiles).
// B fragments loaded coalesced from packed Bp tables, double-buffered in regs.
// Only A goes through LDS (10 KB).
__global__ __launch_bounds__(256) void gemm640_kernel(
    const unsigned short* __restrict__ wbf,   // [N,512] bf16
    const float* __restrict__ X,              // [N,128] fp32
    const unsigned short* __restrict__ Bph,   // packed [80][128][8]
    const unsigned short* __restrict__ Bpl,
    const float* __restrict__ bias,
    float* __restrict__ Xout, int N)
{
    __shared__ unsigned short A_hi[64 * 40];
    __shared__ unsigned short A_lo[64 * 40];

    const int tid  = threadIdx.x;
    const int row0 = blockIdx.x * 64;
    const int lane = tid & 63, wv = tid >> 6;
    const int m    = lane & 31;            // row/col within 32-tile
    const int kh8  = lane >> 5;            // k-half selector (0/1)
    const int rt   = (wv & 1) << 5;        // row tile base 0/32
    const int c0w  = (wv >> 1) << 6;       // col base 0/64

    const int ar  = tid >> 2;              // A stage row 0..63
    const int akv = (tid & 3) << 3;        // A stage k offset 0,8,16,24

    const s8v z8 = {0,0,0,0,0,0,0,0};
    s8v pA = z8;
    float4 pX0, pX1;
    s8v B0[8], B1[8];                      // [h*4 + ct*2 + (0=hi,1=lo)]

    auto loadB = [&](int kc, s8v (&dst)[8]) {
        #pragma unroll
        for (int h = 0; h < 2; ++h) {
            int khg = kc * 4 + h * 2 + kh8;
            #pragma unroll
            for (int ct = 0; ct < 2; ++ct) {
                size_t off = ((size_t)khg * 128 + (c0w + ct * 32 + m)) * 8;
                dst[h * 4 + ct * 2 + 0] = *(const s8v*)&Bph[off];
                dst[h * 4 + ct * 2 + 1] = *(const s8v*)&Bpl[off];
            }
        }
    };
    auto loadA = [&](int kc) {
        int k0 = kc * 32;
        int gr = row0 + ar;
        if (k0 < 512) {
            pA = (gr < N) ? *(const s8v*)&wbf[(size_t)gr * 512 + k0 + akv] : z8;
        } else {
            pX0 = make_float4(0.f, 0.f, 0.f, 0.f);
            pX1 = pX0;
            if (gr < N) {
                pX0 = *(const float4*)&X[(size_t)gr * 128 + (k0 - 512) + akv];
                pX1 = *(const float4*)&X[(size_t)gr * 128 + (k0 - 512) + akv + 4];
            }
        }
    };

    f16v acc0, acc1;
    #pragma unroll
    for (int i = 0; i < 16; ++i) { acc0[i] = 0.f; acc1[i] = 0.f; }

    loadA(0);
    loadB(0, B0);

    auto chunk = [&](int kc, s8v (&cur)[8], s8v (&nxt)[8]) {
        const int k0 = kc * 32;
        if (kc) __syncthreads();
        if (k0 < 512) {
            *(s8v*)&A_hi[ar * 40 + akv] = pA;
        } else {
            float f[8] = {pX0.x, pX0.y, pX0.z, pX0.w, pX1.x, pX1.y, pX1.z, pX1.w};
            s8v h8, l8;
            #pragma unroll
            for (int j = 0; j < 8; ++j) {
                unsigned short h = f2bf(f[j]);
                h8[j] = (short)h;
                l8[j] = (short)f2bf(f[j] - bf2f(h));
            }
            *(s8v*)&A_hi[ar * 40 + akv] = h8;
            *(s8v*)&A_lo[ar * 40 + akv] = l8;
        }
        __syncthreads();
        if (kc < 19) { loadA(kc + 1); loadB(kc + 1, nxt); }

        #pragma unroll
        for (int h = 0; h < 2; ++h) {
            const int off = h * 16 + kh8 * 8;
            s8v aH = *(const s8v*)&A_hi[(rt + m) * 40 + off];
            if (k0 < 512) {
                acc0 = __builtin_amdgcn_mfma_f32_32x32x16_bf16(aH, cur[h*4+1], acc0, 0, 0, 0);
                acc0 = __builtin_amdgcn_mfma_f32_32x32x16_bf16(aH, cur[h*4+0], acc0, 0, 0, 0);
                acc1 = __builtin_amdgcn_mfma_f32_32x32x16_bf16(aH, cur[h*4+3], acc1, 0, 0, 0);
                acc1 = __builtin_amdgcn_mfma_f32_32x32x16_bf16(aH, cur[h*4+2], acc1, 0, 0, 0);
            } else {
                s8v aL = *(const s8v*)&A_lo[(rt + m) * 40 + off];
                acc0 = __builtin_amdgcn_mfma_f32_32x32x16_bf16(aL, cur[h*4+0], acc0, 0, 0, 0);
                acc0 = __builtin_amdgcn_mfma_f32_32x32x16_bf16(aH, cur[h*4+1], acc0, 0, 0, 0);
                acc0 = __builtin_amdgcn_mfma_f32_32x32x16_bf16(aH, cur[h*4+0], acc0, 0, 0, 0);
                acc1 = __builtin_amdgcn_mfma_f32_32x32x16_bf16(aL, cur[h*4+2], acc1, 0, 0, 0);
                acc1 = __builtin_amdgcn_mfma_f32_32x32x16_bf16(aH, cur[h*4+3], acc1, 0, 0, 0);
                acc1 = __builtin_amdgcn_mfma_f32_32x32x16_bf16(aH, cur[h*4+2], acc1, 0, 0, 0);
            }
        }
    };

    #pragma unroll 1
    for (int kc2 = 0; kc2 < 10; ++kc2) {
        chunk(kc2 * 2,     B0, B1);
        chunk(kc2 * 2 + 1, B1, B0);
    }

    // epilogue: 32x32 C/D: col = lane&31, row = (reg&3) + 8*(reg>>2) + 4*(lane>>5)
    const int rbase = rt + (kh8 << 2);
    #pragma unroll
    for (int ct = 0; ct < 2; ++ct) {
        int gc = c0w + ct * 32 + m;
        float bv = bias[gc];
        #pragma unroll
        for (int reg = 0; reg < 16; ++reg) {
            int gr = row0 + rbase + (reg & 3) + ((reg >> 2) << 3);
            if (gr < N) {
                float v = ct ? acc1[reg] : acc0[reg];
                Xout[(size_t)gr * 128 + gc] = fmaxf(v + bv, 0.f);
            }
        }
    }
}

// ---------------- relation context: R2 = relu(DAD @ tab @ W) ----------------
__global__ __launch_bounds__(512) void relctx_kernel(
    const float* __restrict__ DAD,
    const float* __restrict__ tab,
    const float* __restrict__ W,
    float* __restrict__ R2, int NR)
{
    __shared__ float part[4][128];
    __shared__ float r1s[128];
    int r = blockIdx.x;
    int t = threadIdx.x;
    int o = t & 127, q = t >> 7;
    float s = 0.f;
    #pragma unroll 4
    for (int j = q; j < NR; j += 4)
        s = fmaf(DAD[r * NR + j], tab[j * 128 + o], s);
    part[q][o] = s;
    __syncthreads();
    if (t < 128) r1s[t] = part[0][t] + part[1][t] + part[2][t] + part[3][t];
    __syncthreads();
    float s2 = 0.f;
    #pragma unroll 8
    for (int k = q * 32; k < q * 32 + 32; ++k)
        s2 = fmaf(r1s[k], W[k * 128 + o], s2);
    part[q][o] = s2;
    __syncthreads();
    if (t < 128)
        R2[r * 128 + t] = fmaxf(part[0][t] + part[1][t] + part[2][t] + part[3][t], 0.f);
}

// ---------------- gated output ----------------
__global__ __launch_bounds__(256) void output_kernel(
    const int* __restrict__ samples,
    const float* __restrict__ gate_e,
    const float* __restrict__ gate_r,
    const float* __restrict__ ent_emb,
    const float* __restrict__ rel_emb,
    const float* __restrict__ ctx2,
    const float* __restrict__ relctx,
    float* __restrict__ out, int S)
{
    int s = blockIdx.x * 2 + (threadIdx.x >> 7);
    if (s >= S) return;
    int p = blockIdx.y;
    int o = threadIdx.x & 127;
    float v;
    if (p == 1) {
        int idx = samples[s * 3 + 1];
        float g = 1.0f / (1.0f + __expf(-gate_r[o]));
        v = g * rel_emb[idx * 128 + o] + (1.0f - g) * relctx[idx * 128 + o];
    } else {
        int idx = samples[s * 3 + (p == 0 ? 0 : 2)];
        float g = 1.0f / (1.0f + __expf(-gate_e[o]));
        v = g * ent_emb[(size_t)idx * 128 + o] + (1.0f - g) * ctx2[(size_t)idx * 128 + o];
    }
    out[(size_t)p * S * 128 + (size_t)s * 128 + o] = v;
}

extern "C" void kernel_launch(void* const* d_in, const int* in_sizes, int n_in,
                              void* d_out, int out_size, void* d_ws, size_t ws_size,
                              hipStream_t stream)
{
    const int*   entity     = (const int*)d_in[0];
    const int*   edge_index = (const int*)d_in[1];
    const int*   edge_type  = (const int*)d_in[2];
    const float* edge_norm  = (const float*)d_in[3];
    const int*   samples    = (const int*)d_in[4];
    const float* DAD        = (const float*)d_in[5];
    const float* ent_emb    = (const float*)d_in[6];
    const float* rel_emb    = (const float*)d_in[7];
    const float* ent_tab    = (const float*)d_in[8];
    const float* rel_tab    = (const float*)d_in[9];
    const float* Wrel       = (const float*)d_in[10];
    const float* gate_e     = (const float*)d_in[11];
    const float* gate_r     = (const float*)d_in[12];
    const float* basis1     = (const float*)d_in[13];
    const float* att1       = (const float*)d_in[14];
    const float* root1      = (const float*)d_in[15];
    const float* bias1      = (const float*)d_in[16];
    const float* basis2     = (const float*)d_in[17];
    const float* att2       = (const float*)d_in[18];
    const float* root2      = (const float*)d_in[19];
    const float* bias2      = (const float*)d_in[20];

    const int N  = in_sizes[0];        // 50000
    const int E  = in_sizes[2];        // 200000
    const int S  = in_sizes[4] / 3;    // 20000
    const int NR = in_sizes[9] / 128;  // 200

    float* ws      = (float*)d_ws;
    float* X0      = ws;                               // [N,128] f32
    float* X1      = X0 + (size_t)N * 128;             // [N,128] f32
    float4* an1    = (float4*)(X1 + (size_t)N * 128);  // [E+4] float4
    float4* an2    = an1 + (E + 4);                    // [E+4] float4
    unsigned short* wbf = (unsigned short*)(an2 + (E + 4)); // [N,512] bf16
    float* Rc      = (float*)(wbf + (size_t)N * 512);  // [NR,128] f32
    int*   deg     = (int*)(Rc + (size_t)NR * 128);    // [N]
    int*   rstart  = deg + N;                          // [N+1]
    int*   cursor  = rstart + N + 1;                   // [N]
    int*   src_s   = cursor + N;                       // [E+4]
    int*   btot    = src_s + E + 4;                    // [64]
    int*   boff    = btot + 64;                        // [64]
    uintptr_t bt   = ((uintptr_t)(boff + 64) + 15) & ~(uintptr_t)15;
    unsigned short* Bp1h = (unsigned short*)bt;        // [80*128*8] each (160 KB)
    unsigned short* Bp1l = Bp1h + 80 * 128 * 8;
    unsigned short* Bp2h = Bp1l + 80 * 128 * 8;
    unsigned short* Bp2l = Bp2h + 80 * 128 * 8;

    const int egrid = (E + 255) / 256;
    const int ggrid = (N + 63) / 64;
    const int agrid = (N + 7) / 8;
    const int nB    = (N + 1023) / 1024;

    // ---- weight prep + CSR build ----
    bprep_kernel<<<dim3(320, 2), 256, 0, stream>>>(basis1, root1, basis2, root2,
                                                   Bp1h, Bp1l, Bp2h, Bp2l);
    hipMemsetAsync(deg, 0, (size_t)N * sizeof(int), stream);
    hist_kernel<<<egrid, 256, 0, stream>>>(edge_index, deg, E);
    scanA_kernel<<<nB, 1024, 0, stream>>>(deg, rstart, btot, N);
    scanB_kernel<<<1, 64, 0, stream>>>(btot, boff, rstart, nB, N);
    scanC_kernel<<<nB, 1024, 0, stream>>>(rstart, cursor, boff, N);
    fill_kernel<<<egrid, 256, 0, stream>>>(edge_index, edge_type, edge_norm, cursor,
                                           att1, att2, src_s, an1, an2, E);

    // ---- X0 = ent_tab[entity] ----
    x0_kernel<<<(N * 32 + 255) / 256, 256, 0, stream>>>(ent_tab, entity, X0, N);

    // ---- layer 1: X1 = relu([agg(X0)|X0] @ W1) ----
    edge_agg_kernel<<<agrid, 256, 0, stream>>>(X0, rstart, src_s, an1, wbf, N);
    gemm640_kernel<<<ggrid, 256, 0, stream>>>(wbf, X0, Bp1h, Bp1l, bias1, X1, N);

    // ---- layer 2: X0 = relu([agg(X1)|X1] @ W2) ----
    edge_agg_kernel<<<agrid, 256, 0, stream>>>(X1, rstart, src_s, an2, wbf, N);
    gemm640_kernel<<<ggrid, 256, 0, stream>>>(wbf, X1, Bp2h, Bp2l, bias2, X0, N);

    // ---- relation context ----
    relctx_kernel<<<NR, 512, 0, stream>>>(DAD, rel_tab, Wrel, Rc, NR);

    // ---- gated output ----
    output_kernel<<<dim3((S + 1) / 2, 3), 256, 0, stream>>>(
        samples, gate_e, gate_r, ent_emb, rel_emb, X0, Rc, (float*)d_out, S);
}

// Round 11
// 301.995 us; speedup vs baseline: 1.1529x; 1.1529x over previous
//
#include <hip/hip_runtime.h>
#include <hip/hip_bf16.h>

typedef short s8v  __attribute__((ext_vector_type(8)));
typedef float f16v __attribute__((ext_vector_type(16)));

__device__ __forceinline__ unsigned short f2bf(float x) {   // RTN-even
    unsigned u = __float_as_uint(x);
    unsigned r = ((u >> 16) & 1u) + 0x7FFFu;
    return (unsigned short)((u + r) >> 16);
}
__device__ __forceinline__ float bf2f(unsigned short h) {
    return __uint_as_float(((unsigned)h) << 16);
}

// ---------------- X0 = ent_tab[entity] ----------------
__global__ __launch_bounds__(256) void x0_kernel(
    const float* __restrict__ tab, const int* __restrict__ entity,
    float* __restrict__ X0, int N)
{
    int idx = blockIdx.x * 256 + threadIdx.x;
    int n = idx >> 5, l = idx & 31;
    if (n < N) {
        int src = entity[n];
        *(float4*)&X0[(size_t)n * 128 + l * 4] =
            *(const float4*)&tab[(size_t)src * 128 + l * 4];
    }
}

// ---------------- B prep: fragment-packed Bp[k>>3][col][8] hi/lo ----------------
__global__ __launch_bounds__(256) void bprep_kernel(
    const float* __restrict__ basis1, const float* __restrict__ root1,
    const float* __restrict__ basis2, const float* __restrict__ root2,
    unsigned short* __restrict__ Bp1h, unsigned short* __restrict__ Bp1l,
    unsigned short* __restrict__ Bp2h, unsigned short* __restrict__ Bp2l)
{
    int idx = blockIdx.x * 256 + threadIdx.x;    // 0..81919
    int layer = blockIdx.y;
    int n = idx & 127, k = idx >> 7;             // k 0..639
    const float* basis = layer ? basis2 : basis1;
    const float* root  = layer ? root2  : root1;
    float v = (k < 512) ? basis[((k & 3) << 14) + ((k >> 2) << 7) + n]
                        : root[((k - 512) << 7) + n];
    unsigned short h = f2bf(v);
    unsigned short l = f2bf(v - bf2f(h));
    size_t pos = (((size_t)(k >> 3) * 128) + n) * 8 + (k & 7);
    unsigned short* Bh = layer ? Bp2h : Bp1h;
    unsigned short* Bl = layer ? Bp2l : Bp1l;
    Bh[pos] = h;
    Bl[pos] = l;
}

// ---------------- CSR build ----------------
__global__ __launch_bounds__(256) void hist_kernel(
    const int* __restrict__ edge_index, int* __restrict__ deg, int E)
{
    int e = blockIdx.x * 256 + threadIdx.x;
    if (e < E) atomicAdd(&deg[edge_index[E + e]], 1);
}

__global__ __launch_bounds__(1024) void scanA_kernel(
    const int* __restrict__ deg, int* __restrict__ row_start,
    int* __restrict__ btot, int N)
{
    __shared__ int wtot[16];
    __shared__ int woff[16];
    const int tid = threadIdx.x, lane = tid & 63, wid = tid >> 6;
    int i = blockIdx.x * 1024 + tid;
    int v = (i < N) ? deg[i] : 0;
    int x = v;
    #pragma unroll
    for (int d = 1; d < 64; d <<= 1) {
        int t = __shfl_up(x, d, 64);
        if (lane >= d) x += t;
    }
    if (lane == 63) wtot[wid] = x;
    __syncthreads();
    if (wid == 0 && lane < 16) {
        int s = wtot[lane];
        int y = s;
        #pragma unroll
        for (int d = 1; d < 16; d <<= 1) {
            int t = __shfl_up(y, d, 16);
            if (lane >= d) y += t;
        }
        woff[lane] = y - s;
        if (lane == 15) btot[blockIdx.x] = y;
    }
    __syncthreads();
    if (i < N) row_start[i] = woff[wid] + (x - v);
}

__global__ __launch_bounds__(64) void scanB_kernel(
    const int* __restrict__ btot, int* __restrict__ boff,
    int* __restrict__ row_start, int nB, int N)
{
    int t = threadIdx.x;
    int v = (t < nB) ? btot[t] : 0;
    int x = v;
    #pragma unroll
    for (int d = 1; d < 64; d <<= 1) {
        int u = __shfl_up(x, d, 64);
        if (t >= d) x += u;
    }
    if (t < nB) boff[t] = x - v;
    if (t == nB - 1) row_start[N] = x;
}

__global__ __launch_bounds__(1024) void scanC_kernel(
    int* __restrict__ row_start, int* __restrict__ cursor,
    const int* __restrict__ boff, int N)
{
    int i = blockIdx.x * 1024 + threadIdx.x;
    if (i < N) {
        int r = row_start[i] + boff[blockIdx.x];
        row_start[i] = r;
        cursor[i]    = r;
    }
}

// fill: reorder by destination; precompute norm*att for BOTH layers
__global__ __launch_bounds__(256) void fill_kernel(
    const int* __restrict__ edge_index, const int* __restrict__ edge_type,
    const float* __restrict__ edge_norm, int* __restrict__ cursor,
    const float* __restrict__ att1, const float* __restrict__ att2,
    int* __restrict__ src_s, float4* __restrict__ an1, float4* __restrict__ an2, int E)
{
    int e = blockIdx.x * 256 + threadIdx.x;
    if (e >= E) return;
    int dst = edge_index[E + e];
    int et  = edge_type[e];
    float n = edge_norm[e];
    int pos = atomicAdd(&cursor[dst], 1);
    src_s[pos] = edge_index[e];
    float4 a1 = *(const float4*)&att1[(size_t)et * 4];
    float4 a2 = *(const float4*)&att2[(size_t)et * 4];
    an1[pos] = make_float4(n * a1.x, n * a1.y, n * a1.z, n * a1.w);
    an2[pos] = make_float4(n * a2.x, n * a2.y, n * a2.z, n * a2.w);
}

// ---------------- FUSED layer: Xout = relu([agg(X)|X] @ B + bias) ----------------
// Block = 32 nodes, 256 threads. Phase A: edge gather + X rows -> LDS in
// fragment-packed layout Whi[kh][slot][8] (slot = n ^ (kh&31) swizzle), one
// barrier. Phase B: barrier-free MFMA stream; A from LDS, B from packed global
// tables double-buffered 4 steps deep in registers.
__global__ __launch_bounds__(256) void layer_kernel(
    const float* __restrict__ X,              // [N,128] fp32 layer input
    const int* __restrict__ row_start,
    const int* __restrict__ src_s,
    const float4* __restrict__ an,
    const unsigned short* __restrict__ Bph,   // packed [80][128][8]
    const unsigned short* __restrict__ Bpl,
    const float* __restrict__ bias,
    float* __restrict__ Xout, int N)
{
    __shared__ unsigned short Whi[80 * 32 * 8];   // 40 KB
    __shared__ unsigned short Wlo[16 * 32 * 8];   // 8 KB (X lo part, kh 64..79)

    const int tid   = threadIdx.x;
    const int node0 = blockIdx.x * 32;

    // ---- phase A1: gather w for 4 nodes per 32-lane group ----
    {
        int g = tid >> 5, l = tid & 31;     // lane l covers dims 4l..4l+3
        #pragma unroll 1
        for (int i = 0; i < 4; ++i) {
            int n  = g * 4 + i;
            int gn = node0 + n;
            float acc[4][4];
            #pragma unroll
            for (int d = 0; d < 4; ++d)
                #pragma unroll
                for (int b = 0; b < 4; ++b) acc[d][b] = 0.f;
            float inv = 1.f;
            if (gn < N) {
                int s0 = row_start[gn], s1 = row_start[gn + 1];
                for (int p = s0; p < s1; p += 4) {
                    int i1 = min(p + 1, s1 - 1);
                    int i2 = min(p + 2, s1 - 1);
                    int i3 = min(p + 3, s1 - 1);
                    int sA = src_s[p],  sB = src_s[i1];
                    int sC = src_s[i2], sD = src_s[i3];
                    float4 aA = an[p],  aB = an[i1];
                    float4 aC = an[i2], aD = an[i3];
                    if (p + 1 >= s1) aB = make_float4(0.f, 0.f, 0.f, 0.f);
                    if (p + 2 >= s1) aC = make_float4(0.f, 0.f, 0.f, 0.f);
                    if (p + 3 >= s1) aD = make_float4(0.f, 0.f, 0.f, 0.f);
                    float4 xA = *(const float4*)&X[(size_t)sA * 128 + (l << 2)];
                    float4 xB = *(const float4*)&X[(size_t)sB * 128 + (l << 2)];
                    float4 xC = *(const float4*)&X[(size_t)sC * 128 + (l << 2)];
                    float4 xD = *(const float4*)&X[(size_t)sD * 128 + (l << 2)];
                    float xsA[4] = {xA.x, xA.y, xA.z, xA.w};
                    float xsB[4] = {xB.x, xB.y, xB.z, xB.w};
                    float xsC[4] = {xC.x, xC.y, xC.z, xC.w};
                    float xsD[4] = {xD.x, xD.y, xD.z, xD.w};
                    #pragma unroll
                    for (int d = 0; d < 4; ++d) {
                        acc[d][0] = fmaf(aA.x, xsA[d], fmaf(aB.x, xsB[d], fmaf(aC.x, xsC[d], fmaf(aD.x, xsD[d], acc[d][0]))));
                        acc[d][1] = fmaf(aA.y, xsA[d], fmaf(aB.y, xsB[d], fmaf(aC.y, xsC[d], fmaf(aD.y, xsD[d], acc[d][1]))));
                        acc[d][2] = fmaf(aA.z, xsA[d], fmaf(aB.z, xsB[d], fmaf(aC.z, xsC[d], fmaf(aD.z, xsD[d], acc[d][2]))));
                        acc[d][3] = fmaf(aA.w, xsA[d], fmaf(aB.w, xsB[d], fmaf(aC.w, xsC[d], fmaf(aD.w, xsD[d], acc[d][3]))));
                    }
                }
                inv = 1.0f / fmaxf((float)(s1 - s0), 1.0f);
            }
            // store: k = 16l + 4d + b -> kh = 2l + (d>>1), j = (d&1)*4 + b
            #pragma unroll
            for (int d = 0; d < 4; ++d) {
                int kh   = 2 * l + (d >> 1);
                int slot = n ^ (kh & 31);
                ushort4 h;
                h.x = f2bf(acc[d][0] * inv);
                h.y = f2bf(acc[d][1] * inv);
                h.z = f2bf(acc[d][2] * inv);
                h.w = f2bf(acc[d][3] * inv);
                *(ushort4*)&Whi[(kh * 32 + slot) * 8 + (d & 1) * 4] = h;
            }
        }
    }

    // ---- phase A2: X rows (k 512..639) -> hi/lo bf16, kh 64..79 ----
    {
        int r  = tid >> 3;                  // 0..31
        int kq = (tid & 7) * 16;            // 0..112
        int gn = node0 + r;
        float4 v0 = make_float4(0,0,0,0), v1 = v0, v2 = v0, v3 = v0;
        if (gn < N) {
            const float* xp = &X[(size_t)gn * 128 + kq];
            v0 = *(const float4*)(xp + 0);
            v1 = *(const float4*)(xp + 4);
            v2 = *(const float4*)(xp + 8);
            v3 = *(const float4*)(xp + 12);
        }
        float f[16] = {v0.x, v0.y, v0.z, v0.w, v1.x, v1.y, v1.z, v1.w,
                       v2.x, v2.y, v2.z, v2.w, v3.x, v3.y, v3.z, v3.w};
        #pragma unroll
        for (int i = 0; i < 2; ++i) {
            int kh   = 64 + (tid & 7) * 2 + i;
            int slot = r ^ (kh & 31);
            s8v h8, l8;
            #pragma unroll
            for (int j = 0; j < 8; ++j) {
                unsigned short h = f2bf(f[i * 8 + j]);
                h8[j] = (short)h;
                l8[j] = (short)f2bf(f[i * 8 + j] - bf2f(h));
            }
            *(s8v*)&Whi[(kh * 32 + slot) * 8] = h8;
            *(s8v*)&Wlo[((kh - 64) * 32 + slot) * 8] = l8;
        }
    }
    __syncthreads();

    // ---- phase B: barrier-free MFMA stream ----
    const int lane = tid & 63, wv = tid >> 6;
    const int m    = lane & 31;             // col within wave tile / A row
    const int kh8  = lane >> 5;             // k-half selector
    const int c0   = wv << 5;               // cols c0..c0+31

    f16v acc;
    #pragma unroll
    for (int i = 0; i < 16; ++i) acc[i] = 0.f;

    s8v Bb[2][8];                           // [buf][q*2 + (0=hi,1=lo)], 4 steps/buf
    auto loadB4 = [&](int g, int buf) {
        #pragma unroll
        for (int q = 0; q < 4; ++q) {
            int khg = (g * 4 + q) * 2 + kh8;
            size_t off = ((size_t)khg * 128 + c0 + m) * 8;
            Bb[buf][q * 2 + 0] = *(const s8v*)&Bph[off];
            Bb[buf][q * 2 + 1] = *(const s8v*)&Bpl[off];
        }
    };
    loadB4(0, 0);

    #pragma unroll
    for (int g = 0; g < 10; ++g) {          // 40 steps of K=16
        int buf = g & 1;
        if (g < 9) loadB4(g + 1, buf ^ 1);
        #pragma unroll
        for (int q = 0; q < 4; ++q) {
            int s    = g * 4 + q;
            int khg  = s * 2 + kh8;
            int slot = m ^ (khg & 31);
            s8v aH = *(const s8v*)&Whi[(khg * 32 + slot) * 8];
            if (s >= 32) {                  // X part: add aL*bH
                s8v aL = *(const s8v*)&Wlo[((khg - 64) * 32 + slot) * 8];
                acc = __builtin_amdgcn_mfma_f32_32x32x16_bf16(aL, Bb[buf][q*2], acc, 0, 0, 0);
            }
            acc = __builtin_amdgcn_mfma_f32_32x32x16_bf16(aH, Bb[buf][q*2+1], acc, 0, 0, 0);
            acc = __builtin_amdgcn_mfma_f32_32x32x16_bf16(aH, Bb[buf][q*2+0], acc, 0, 0, 0);
        }
    }

    // epilogue: 32x32 C/D: col = lane&31, row = (reg&3) + 8*(reg>>2) + 4*(lane>>5)
    int gc = c0 + m;
    float bv = bias[gc];
    const int rbase = kh8 << 2;
    #pragma unroll
    for (int reg = 0; reg < 16; ++reg) {
        int gr = node0 + rbase + (reg & 3) + ((reg >> 2) << 3);
        if (gr < N)
            Xout[(size_t)gr * 128 + gc] = fmaxf(acc[reg] + bv, 0.f);
    }
}

// ---------------- relation context: R2 = relu(DAD @ tab @ W) ----------------
__global__ __launch_bounds__(512) void relctx_kernel(
    const float* __restrict__ DAD,
    const float* __restrict__ tab,
    const float* __restrict__ W,
    float* __restrict__ R2, int NR)
{
    __shared__ float part[4][128];
    __shared__ float r1s[128];
    int r = blockIdx.x;
    int t = threadIdx.x;
    int o = t & 127, q = t >> 7;
    float s = 0.f;
    #pragma unroll 4
    for (int j = q; j < NR; j += 4)
        s = fmaf(DAD[r * NR + j], tab[j * 128 + o], s);
    part[q][o] = s;
    __syncthreads();
    if (t < 128) r1s[t] = part[0][t] + part[1][t] + part[2][t] + part[3][t];
    __syncthreads();
    float s2 = 0.f;
    #pragma unroll 8
    for (int k = q * 32; k < q * 32 + 32; ++k)
        s2 = fmaf(r1s[k], W[k * 128 + o], s2);
    part[q][o] = s2;
    __syncthreads();
    if (t < 128)
        R2[r * 128 + t] = fmaxf(part[0][t] + part[1][t] + part[2][t] + part[3][t], 0.f);
}

// ---------------- gated output ----------------
__global__ __launch_bounds__(256) void output_kernel(
    const int* __restrict__ samples,
    const float* __restrict__ gate_e,
    const float* __restrict__ gate_r,
    const float* __restrict__ ent_emb,
    const float* __restrict__ rel_emb,
    const float* __restrict__ ctx2,
    const float* __restrict__ relctx,
    float* __restrict__ out, int S)
{
    int s = blockIdx.x * 2 + (threadIdx.x >> 7);
    if (s >= S) return;
    int p = blockIdx.y;
    int o = threadIdx.x & 127;
    float v;
    if (p == 1) {
        int idx = samples[s * 3 + 1];
        float g = 1.0f / (1.0f + __expf(-gate_r[o]));
        v = g * rel_emb[idx * 128 + o] + (1.0f - g) * relctx[idx * 128 + o];
    } else {
        int idx = samples[s * 3 + (p == 0 ? 0 : 2)];
        float g = 1.0f / (1.0f + __expf(-gate_e[o]));
        v = g * ent_emb[(size_t)idx * 128 + o] + (1.0f - g) * ctx2[(size_t)idx * 128 + o];
    }
    out[(size_t)p * S * 128 + (size_t)s * 128 + o] = v;
}

extern "C" void kernel_launch(void* const* d_in, const int* in_sizes, int n_in,
                              void* d_out, int out_size, void* d_ws, size_t ws_size,
                              hipStream_t stream)
{
    const int*   entity     = (const int*)d_in[0];
    const int*   edge_index = (const int*)d_in[1];
    const int*   edge_type  = (const int*)d_in[2];
    const float* edge_norm  = (const float*)d_in[3];
    const int*   samples    = (const int*)d_in[4];
    const float* DAD        = (const float*)d_in[5];
    const float* ent_emb    = (const float*)d_in[6];
    const float* rel_emb    = (const float*)d_in[7];
    const float* ent_tab    = (const float*)d_in[8];
    const float* rel_tab    = (const float*)d_in[9];
    const float* Wrel       = (const float*)d_in[10];
    const float* gate_e     = (const float*)d_in[11];
    const float* gate_r     = (const float*)d_in[12];
    const float* basis1     = (const float*)d_in[13];
    const float* att1       = (const float*)d_in[14];
    const float* root1      = (const float*)d_in[15];
    const float* bias1      = (const float*)d_in[16];
    const float* basis2     = (const float*)d_in[17];
    const float* att2       = (const float*)d_in[18];
    const float* root2      = (const float*)d_in[19];
    const float* bias2      = (const float*)d_in[20];

    const int N  = in_sizes[0];        // 50000
    const int E  = in_sizes[2];        // 200000
    const int S  = in_sizes[4] / 3;    // 20000
    const int NR = in_sizes[9] / 128;  // 200

    float* ws      = (float*)d_ws;
    float* X0      = ws;                               // [N,128] f32
    float* X1      = X0 + (size_t)N * 128;             // [N,128] f32
    float4* an1    = (float4*)(X1 + (size_t)N * 128);  // [E+4] float4
    float4* an2    = an1 + (E + 4);                    // [E+4] float4
    float* Rc      = (float*)(an2 + (E + 4));          // [NR,128] f32
    int*   deg     = (int*)(Rc + (size_t)NR * 128);    // [N]
    int*   rstart  = deg + N;                          // [N+1]
    int*   cursor  = rstart + N + 1;                   // [N]
    int*   src_s   = cursor + N;                       // [E+4]
    int*   btot    = src_s + E + 4;                    // [64]
    int*   boff    = btot + 64;                        // [64]
    uintptr_t bt   = ((uintptr_t)(boff + 64) + 15) & ~(uintptr_t)15;
    unsigned short* Bp1h = (unsigned short*)bt;        // [80*128*8] each (160 KB)
    unsigned short* Bp1l = Bp1h + 80 * 128 * 8;
    unsigned short* Bp2h = Bp1l + 80 * 128 * 8;
    unsigned short* Bp2l = Bp2h + 80 * 128 * 8;

    const int egrid = (E + 255) / 256;
    const int lgrid = (N + 31) / 32;
    const int nB    = (N + 1023) / 1024;

    // ---- weight prep + CSR build ----
    bprep_kernel<<<dim3(320, 2), 256, 0, stream>>>(basis1, root1, basis2, root2,
                                                   Bp1h, Bp1l, Bp2h, Bp2l);
    hipMemsetAsync(deg, 0, (size_t)N * sizeof(int), stream);
    hist_kernel<<<egrid, 256, 0, stream>>>(edge_index, deg, E);
    scanA_kernel<<<nB, 1024, 0, stream>>>(deg, rstart, btot, N);
    scanB_kernel<<<1, 64, 0, stream>>>(btot, boff, rstart, nB, N);
    scanC_kernel<<<nB, 1024, 0, stream>>>(rstart, cursor, boff, N);
    fill_kernel<<<egrid, 256, 0, stream>>>(edge_index, edge_type, edge_norm, cursor,
                                           att1, att2, src_s, an1, an2, E);

    // ---- X0 = ent_tab[entity] ----
    x0_kernel<<<(N * 32 + 255) / 256, 256, 0, stream>>>(ent_tab, entity, X0, N);

    // ---- layer 1 (fused): X1 = relu([agg(X0)|X0] @ W1) ----
    layer_kernel<<<lgrid, 256, 0, stream>>>(X0, rstart, src_s, an1, Bp1h, Bp1l, bias1, X1, N);

    // ---- layer 2 (fused): X0 = relu([agg(X1)|X1] @ W2) ----
    layer_kernel<<<lgrid, 256, 0, stream>>>(X1, rstart, src_s, an2, Bp2h, Bp2l, bias2, X0, N);

    // ---- relation context ----
    relctx_kernel<<<NR, 512, 0, stream>>>(DAD, rel_tab, Wrel, Rc, NR);

    // ---- gated output ----
    output_kernel<<<dim3((S + 1) / 2, 3), 256, 0, stream>>>(
        samples, gate_e, gate_r, ent_emb, rel_emb, X0, Rc, (float*)d_out, S);
}